// Round 1
// baseline (277.422 us; speedup 1.0000x reference)
//
#include <hip/hip_runtime.h>
#include <hip/hip_bf16.h>

// LossUnsupervised fused kernel.
// Stage 1 (fused_main, 1024 blocks x 512 thr): per block of 256 rows:
//   - stage m (256x128 f32) into LDS as bf16 hi/lo in MFMA B-frag order (128 KiB)
//   - split-bf16 MFMA GEMM q = x @ m^T (3 terms: hh + lh + hl), fp32 acc
//   - row norms accumulated during A-loads; epilogue: logits = -max(d2,0)/s1^2,
//     online softmax entropy H = logS - T/S, block partial -> ws[bid]
// Stage 2 (finalize, 1 block): intra = mean, inter entropy over centers, out[3].

#define N_ROWS 262144
#define KC 256
#define FD 128

typedef __attribute__((ext_vector_type(8))) short bf16x8;   // 8 bf16 in 4 VGPRs
typedef __attribute__((ext_vector_type(4))) float f32x4;
typedef __attribute__((ext_vector_type(4))) unsigned short u16x4;

__device__ __forceinline__ unsigned short bf16_rne(float x) {
    unsigned int u = __float_as_uint(x);
    u += 0x7FFFu + ((u >> 16) & 1u);
    return (unsigned short)(u >> 16);
}
__device__ __forceinline__ float bf16f(unsigned short h) {
    return __uint_as_float(((unsigned int)h) << 16);
}

__global__ __launch_bounds__(512, 2) void fused_main(
    const float* __restrict__ x, const float* __restrict__ m,
    const float* __restrict__ s1, float* __restrict__ blocksum)
{
    extern __shared__ char smem[];
    unsigned short* mhi = (unsigned short*)smem;        // 32768 bf16 (64 KiB)
    unsigned short* mlo = mhi + 32768;                  // 32768 bf16 (64 KiB)
    float* mn2  = (float*)(mlo + 32768);                // 256
    float* invs = mn2 + 256;                            // 256
    float* entw = invs + 256;                           // 8

    const int tid  = threadIdx.x;
    const int lane = tid & 63;
    const int w    = tid >> 6;            // wave 0..7
    const int rw   = lane & 15;           // A row / B col within frag
    const int blkl = lane >> 4;           // k-block 0..3

    if (tid < 256) {
        mn2[tid] = 0.0f;
        float sv = s1[tid];
        invs[tid] = 1.0f / (sv * sv);
    }
    __syncthreads();

    // ---- stage m into LDS in B-frag order, accumulate |m_k|^2 ----
    for (int it = 0; it < 16; ++it) {
        int j  = tid + 512 * it;          // float4 index, 8192 total
        int k  = j >> 5;                  // cluster row (32 float4 per row)
        int f0 = (j & 31) << 2;           // feature offset
        float4 v = reinterpret_cast<const float4*>(m)[j];
        float pn = v.x*v.x + v.y*v.y + v.z*v.z + v.w*v.w;
        // lanes 0..31 of a wave share k; reduce then 1 atomic per 32 lanes
        #pragma unroll
        for (int msk = 1; msk <= 16; msk <<= 1) pn += __shfl_xor(pn, msk);
        if ((lane & 31) == 0) atomicAdd(&mn2[k], pn);

        int c = k >> 4, n = k & 15, s = f0 >> 5, blk = (f0 >> 3) & 3, i0 = f0 & 7;
        int elem = ((c * 4 + s) * 64 + blk * 16 + n) * 8 + i0;
        float xs[4] = {v.x, v.y, v.z, v.w};
        u16x4 hh, ll;
        #pragma unroll
        for (int q = 0; q < 4; ++q) {
            unsigned short h = bf16_rne(xs[q]);
            float r = xs[q] - bf16f(h);
            hh[q] = h;
            ll[q] = bf16_rne(r);
        }
        *(u16x4*)(mhi + elem) = hh;
        *(u16x4*)(mlo + elem) = ll;
    }
    __syncthreads();

    // ---- main GEMM: wave handles 32 rows (2 x 16-row frags), all 256 cols ----
    const int rbase = blockIdx.x * 256 + w * 32;
    f32x4 acc[16][2];
    #pragma unroll
    for (int c = 0; c < 16; ++c)
        #pragma unroll
        for (int r = 0; r < 2; ++r)
            acc[c][r] = f32x4{0.f, 0.f, 0.f, 0.f};

    float norm2p[2] = {0.f, 0.f};

    float4 u[2], v[2];
    #pragma unroll
    for (int rf = 0; rf < 2; ++rf) {
        const float* p = x + (size_t)(rbase + rf * 16 + rw) * FD + blkl * 8;
        u[rf] = *(const float4*)p;
        v[rf] = *(const float4*)(p + 4);
    }

    #pragma unroll
    for (int s = 0; s < 4; ++s) {
        bf16x8 ahi[2], alo[2];
        #pragma unroll
        for (int rf = 0; rf < 2; ++rf) {
            float xs[8] = {u[rf].x, u[rf].y, u[rf].z, u[rf].w,
                           v[rf].x, v[rf].y, v[rf].z, v[rf].w};
            #pragma unroll
            for (int q = 0; q < 8; ++q) {
                norm2p[rf] += xs[q] * xs[q];
                unsigned short h = bf16_rne(xs[q]);
                float r = xs[q] - bf16f(h);
                ahi[rf][q] = (short)h;
                alo[rf][q] = (short)bf16_rne(r);
            }
        }
        if (s < 3) {  // prefetch next k-step's A while MFMAs run
            #pragma unroll
            for (int rf = 0; rf < 2; ++rf) {
                const float* p = x + (size_t)(rbase + rf * 16 + rw) * FD + (s + 1) * 32 + blkl * 8;
                u[rf] = *(const float4*)p;
                v[rf] = *(const float4*)(p + 4);
            }
        }
        #pragma unroll
        for (int c = 0; c < 16; ++c) {
            const int eoff = ((c * 4 + s) * 64 + lane) * 8;
            bf16x8 bh = *(const bf16x8*)(mhi + eoff);   // lane-linear: conflict-free
            bf16x8 bl = *(const bf16x8*)(mlo + eoff);
            #pragma unroll
            for (int rf = 0; rf < 2; ++rf) {
                acc[c][rf] = __builtin_amdgcn_mfma_f32_16x16x32_bf16(alo[rf], bh, acc[c][rf], 0, 0, 0);
                acc[c][rf] = __builtin_amdgcn_mfma_f32_16x16x32_bf16(ahi[rf], bl, acc[c][rf], 0, 0, 0);
                acc[c][rf] = __builtin_amdgcn_mfma_f32_16x16x32_bf16(ahi[rf], bh, acc[c][rf], 0, 0, 0);
            }
        }
    }

    // ---- epilogue: per-row softmax entropy ----
    float arow[2][4];
    #pragma unroll
    for (int rf = 0; rf < 2; ++rf) {
        float n2 = norm2p[rf];
        n2 += __shfl_xor(n2, 16);
        n2 += __shfl_xor(n2, 32);
        float a2 = 2.0f / fmaxf(sqrtf(n2), 1e-12f);   // lane holds row rw's scale
        #pragma unroll
        for (int reg = 0; reg < 4; ++reg)
            arow[rf][reg] = __shfl(a2, blkl * 4 + reg);  // scale of the C/D row
    }

    float bkv[16], isv[16];
    #pragma unroll
    for (int c = 0; c < 16; ++c) {
        int col = c * 16 + rw;
        bkv[c] = 1.0f + mn2[col];     // |xn|^2 + |m_k|^2
        isv[c] = invs[col];
    }

    float ent = 0.0f;
    #pragma unroll
    for (int rf = 0; rf < 2; ++rf) {
        #pragma unroll
        for (int reg = 0; reg < 4; ++reg) {
            float a2 = arow[rf][reg];
            float lv[16];
            float mx = -1e30f;
            #pragma unroll
            for (int c = 0; c < 16; ++c) {
                // logit = -max(d2,0)/s^2 = min(2*q/|x| - (1+mn2), 0) * invs
                float t = fminf(a2 * acc[c][rf][reg] - bkv[c], 0.0f) * isv[c];
                lv[c] = t;
                mx = fmaxf(mx, t);
            }
            mx = fmaxf(mx, __shfl_xor(mx, 1));
            mx = fmaxf(mx, __shfl_xor(mx, 2));
            mx = fmaxf(mx, __shfl_xor(mx, 4));
            mx = fmaxf(mx, __shfl_xor(mx, 8));
            float S = 0.f, T = 0.f;
            #pragma unroll
            for (int c = 0; c < 16; ++c) {
                float d = lv[c] - mx;
                float e = __expf(d);
                S += e;
                T += d * e;
            }
            #pragma unroll
            for (int msk = 1; msk <= 8; msk <<= 1) {
                S += __shfl_xor(S, msk);
                T += __shfl_xor(T, msk);
            }
            if (rw == 0) ent += __logf(S) - T / S;   // H = logS - T/S
        }
    }
    ent += __shfl_xor(ent, 16);
    ent += __shfl_xor(ent, 32);
    if (lane == 0) entw[w] = ent;
    __syncthreads();
    if (tid == 0) {
        float b = 0.f;
        #pragma unroll
        for (int i = 0; i < 8; ++i) b += entw[i];
        blocksum[blockIdx.x] = b;
    }
}

__global__ void finalize(const float* __restrict__ blocksum,
                         const float* __restrict__ m,
                         const float* __restrict__ s2,
                         float* __restrict__ out)
{
    __shared__ float xm[128];
    __shared__ double dred[4];
    __shared__ float redM[4], redS[4], redT[4];
    const int tid = threadIdx.x;
    const int lane = tid & 63;
    const int w = tid >> 6;

    // intra partial sums (1024 floats) in double
    double ds = 0.0;
    for (int i = tid; i < 1024; i += 256) ds += (double)blocksum[i];
    #pragma unroll
    for (int msk = 1; msk <= 32; msk <<= 1) ds += __shfl_xor(ds, msk);
    if (lane == 0) dred[w] = ds;

    // mean center
    if (tid < 128) {
        float sum = 0.f;
        for (int k = 0; k < 256; ++k) sum += m[k * 128 + tid];
        xm[tid] = sum * (1.0f / 256.0f);
    }
    __syncthreads();

    // per-center logit
    float d2 = 0.f;
    for (int f = 0; f < 128; ++f) {
        float df = xm[f] - m[tid * 128 + f];
        d2 += df * df;
    }
    float dd = sqrtf(d2);
    float r = dd / s2[tid];
    float lg = -(r * r);

    float mx = lg;
    #pragma unroll
    for (int msk = 1; msk <= 32; msk <<= 1) mx = fmaxf(mx, __shfl_xor(mx, msk));
    if (lane == 0) redM[w] = mx;
    __syncthreads();
    float bmx = fmaxf(fmaxf(redM[0], redM[1]), fmaxf(redM[2], redM[3]));
    float d = lg - bmx;
    float e = __expf(d);
    float S = e, T = d * e;
    #pragma unroll
    for (int msk = 1; msk <= 32; msk <<= 1) {
        S += __shfl_xor(S, msk);
        T += __shfl_xor(T, msk);
    }
    if (lane == 0) { redS[w] = S; redT[w] = T; }
    __syncthreads();
    if (tid == 0) {
        float Sa = redS[0] + redS[1] + redS[2] + redS[3];
        float Ta = redT[0] + redT[1] + redT[2] + redT[3];
        float inter = __logf(Sa) - Ta / Sa;
        double intra_d = dred[0] + dred[1] + dred[2] + dred[3];
        float intra = (float)(intra_d / (double)N_ROWS);
        out[0] = intra - inter;   // LAMB = 1
        out[1] = intra;
        out[2] = inter;
    }
}

extern "C" void kernel_launch(void* const* d_in, const int* in_sizes, int n_in,
                              void* d_out, int out_size, void* d_ws, size_t ws_size,
                              hipStream_t stream) {
    const float* x  = (const float*)d_in[0];
    const float* m  = (const float*)d_in[1];
    const float* s1 = (const float*)d_in[2];
    const float* s2 = (const float*)d_in[3];
    float* out = (float*)d_out;
    float* blocksum = (float*)d_ws;           // 1024 floats

    const size_t shbytes = (size_t)(32768 + 32768) * 2 + (256 + 256 + 8) * 4;
    static bool attr_set = false;             // host-side metadata, not stream work
    if (!attr_set) {
        (void)hipFuncSetAttribute((const void*)fused_main,
                                  hipFuncAttributeMaxDynamicSharedMemorySize,
                                  (int)shbytes);
        attr_set = true;
    }

    fused_main<<<dim3(1024), dim3(512), shbytes, stream>>>(x, m, s1, blocksum);
    finalize<<<dim3(1), dim3(256), 0, stream>>>(blocksum, m, s2, out);
}

// Round 2
// 225.896 us; speedup vs baseline: 1.2281x; 1.2281x over previous
//
#include <hip/hip_runtime.h>
#include <hip/hip_bf16.h>

// LossUnsupervised v2.
// prep (32x256): m -> bf16 frag-order (ws), |m_k|^2, 1/s1^2.
// fused_main (2048x512, 2 blocks/CU): stage 64KB m-hi + 2KB aux to LDS,
//   2-term split-bf16 MFMA (exact-split A x bf16 B), fused normalize +
//   softmax-entropy epilogue (no max pass: logits in [-4/s^2, 0]).
// finalize (1x256): blocksum reduce + inter-center entropy, out[3].

#define N_ROWS 262144

typedef __attribute__((ext_vector_type(8))) short bf16x8;
typedef __attribute__((ext_vector_type(4))) float f32x4;
typedef __attribute__((ext_vector_type(4))) unsigned short u16x4;

__device__ __forceinline__ unsigned short bf16_rne(float x) {
    unsigned int u = __float_as_uint(x);
    u += 0x7FFFu + ((u >> 16) & 1u);
    return (unsigned short)(u >> 16);
}
__device__ __forceinline__ float bf16f(unsigned short h) {
    return __uint_as_float(((unsigned int)h) << 16);
}

__global__ __launch_bounds__(256) void prep(
    const float* __restrict__ m, const float* __restrict__ s1,
    unsigned short* __restrict__ mhi_g, float* __restrict__ mn2_g,
    float* __restrict__ invs_g)
{
    const int t    = threadIdx.x;
    const int lane = t & 63;
    const int k    = blockIdx.x * 8 + (t >> 5);   // center index
    const int f4   = t & 31;                      // float4 within row
    float4 v = reinterpret_cast<const float4*>(m)[k * 32 + f4];
    float pn = v.x*v.x + v.y*v.y + v.z*v.z + v.w*v.w;
    #pragma unroll
    for (int msk = 1; msk <= 16; msk <<= 1) pn += __shfl_xor(pn, msk);
    if ((lane & 31) == 0) {
        mn2_g[k] = pn;
        float sv = s1[k];
        invs_g[k] = 1.0f / (sv * sv);
    }
    const int f0 = f4 << 2;
    const int c = k >> 4, n = k & 15, s = f0 >> 5, blk = (f0 >> 3) & 3, i0 = f0 & 7;
    const int elem = ((c * 4 + s) * 64 + blk * 16 + n) * 8 + i0;
    float xs[4] = {v.x, v.y, v.z, v.w};
    u16x4 hh;
    #pragma unroll
    for (int q = 0; q < 4; ++q) hh[q] = bf16_rne(xs[q]);
    *(u16x4*)(mhi_g + elem) = hh;
}

__global__ __launch_bounds__(512, 4) void fused_main(
    const float* __restrict__ x, const unsigned short* __restrict__ mhi_g,
    const float* __restrict__ mn2_g, const float* __restrict__ invs_g,
    float* __restrict__ blocksum)
{
    extern __shared__ char smem[];
    unsigned short* mhi = (unsigned short*)smem;          // 64 KiB, frag order
    float* mn2  = (float*)(smem + 65536);                 // 256 f32
    float* invs = (float*)(smem + 65536 + 1024);          // 256 f32
    float* entw = (float*)(smem + 65536 + 2048);          // 8 f32

    const int tid  = threadIdx.x;
    const int lane = tid & 63;
    const int w    = tid >> 6;       // wave 0..7
    const int rw   = lane & 15;      // row within A frag / col within C
    const int blkl = lane >> 4;      // k-block 0..3

    // ---- stage: 64KB mhi + aux, all lane-linear (conflict-free b128) ----
    {
        const uint4* s4 = (const uint4*)mhi_g;
        uint4* d4 = (uint4*)mhi;
        #pragma unroll
        for (int it = 0; it < 8; ++it) d4[tid + it * 512] = s4[tid + it * 512];
        if (tid < 256) { mn2[tid] = mn2_g[tid]; invs[tid] = invs_g[tid]; }
    }
    __syncthreads();

    // ---- k-loop: wave owns 16 rows, all 256 cols; acc = 16 x f32x4 ----
    const int rbase = blockIdx.x * 128 + w * 16;
    const float* xrow = x + (size_t)(rbase + rw) * 128 + blkl * 8;

    f32x4 acc[16];
    #pragma unroll
    for (int c = 0; c < 16; ++c) acc[c] = f32x4{0.f, 0.f, 0.f, 0.f};

    float n2 = 0.0f;
    float4 u = *(const float4*)(xrow);
    float4 v = *(const float4*)(xrow + 4);

    #pragma unroll
    for (int s = 0; s < 4; ++s) {
        bf16x8 ahi, alo;
        {
            float xs[8] = {u.x, u.y, u.z, u.w, v.x, v.y, v.z, v.w};
            #pragma unroll
            for (int q = 0; q < 8; ++q) {
                n2 += xs[q] * xs[q];
                unsigned short h = bf16_rne(xs[q]);
                float r = xs[q] - bf16f(h);
                ahi[q] = (short)h;
                alo[q] = (short)bf16_rne(r);
            }
        }
        if (s < 3) {   // prefetch next k-step
            u = *(const float4*)(xrow + (s + 1) * 32);
            v = *(const float4*)(xrow + (s + 1) * 32 + 4);
        }
        #pragma unroll
        for (int c = 0; c < 16; ++c) {
            bf16x8 bh = *(const bf16x8*)(mhi + ((c * 4 + s) * 64 + lane) * 8);
            acc[c] = __builtin_amdgcn_mfma_f32_16x16x32_bf16(alo, bh, acc[c], 0, 0, 0);
            acc[c] = __builtin_amdgcn_mfma_f32_16x16x32_bf16(ahi, bh, acc[c], 0, 0, 0);
        }
    }

    // ---- epilogue: per-row softmax entropy, max = 0 (logits <= 0, >= -4/s^2) ----
    n2 += __shfl_xor(n2, 16);
    n2 += __shfl_xor(n2, 32);
    float a2 = 2.0f / fmaxf(sqrtf(n2), 1e-12f);
    float arow[4];
    #pragma unroll
    for (int reg = 0; reg < 4; ++reg)
        arow[reg] = __shfl(a2, blkl * 4 + reg);   // scale of C/D row blkl*4+reg

    float bkv[16], isv[16];
    #pragma unroll
    for (int c = 0; c < 16; ++c) {
        int col = c * 16 + rw;
        bkv[c] = 1.0f + mn2[col];
        isv[c] = invs[col];
    }

    float ent = 0.0f;
    #pragma unroll
    for (int reg = 0; reg < 4; ++reg) {
        float S = 0.f, T = 0.f;
        #pragma unroll
        for (int c = 0; c < 16; ++c) {
            float l = fminf(arow[reg] * acc[c][reg] - bkv[c], 0.0f) * isv[c];
            float e = __expf(l);
            S += e;
            T += l * e;
        }
        #pragma unroll
        for (int msk = 1; msk <= 8; msk <<= 1) {
            S += __shfl_xor(S, msk);
            T += __shfl_xor(T, msk);
        }
        if (rw == 0) ent += __logf(S) - T / S;    // H = logS - T/S
    }
    ent += __shfl_xor(ent, 16);
    ent += __shfl_xor(ent, 32);
    if (lane == 0) entw[w] = ent;
    __syncthreads();
    if (tid == 0) {
        float b = 0.f;
        #pragma unroll
        for (int i = 0; i < 8; ++i) b += entw[i];
        blocksum[blockIdx.x] = b;
    }
}

__global__ __launch_bounds__(256) void finalize(
    const float* __restrict__ blocksum, const float* __restrict__ m,
    const float* __restrict__ s2, float* __restrict__ out)
{
    __shared__ float xmp[256];
    __shared__ float xm[128];
    __shared__ double dred[4];
    __shared__ float redM[4], redS[4], redT[4];
    const int tid = threadIdx.x;
    const int lane = tid & 63;
    const int w = tid >> 6;

    // intra partials (2048) in double
    double ds = 0.0;
    #pragma unroll
    for (int j = 0; j < 8; ++j) ds += (double)blocksum[tid + 256 * j];
    #pragma unroll
    for (int msk = 1; msk <= 32; msk <<= 1) ds += __shfl_xor(ds, msk);
    if (lane == 0) dred[w] = ds;

    // mean center: coalesced column sums (lane = feature)
    {
        const int f = tid & 127, half = tid >> 7;
        const float* mp = m + (size_t)half * 128 * 128 + f;
        float cs = 0.f;
        #pragma unroll 8
        for (int k = 0; k < 128; ++k) cs += mp[(size_t)k * 128];
        xmp[tid] = cs;
    }
    __syncthreads();
    if (tid < 128) xm[tid] = (xmp[tid] + xmp[tid + 128]) * (1.0f / 256.0f);
    __syncthreads();

    // per-center logit (float4 row gather, 128KB total, L2-hot)
    float d2 = 0.f;
    {
        const float4* mr = (const float4*)(m + (size_t)tid * 128);
        const float4* xv4 = (const float4*)xm;
        #pragma unroll 8
        for (int j = 0; j < 32; ++j) {
            float4 mv = mr[j], xv = xv4[j];
            float dx = xv.x - mv.x, dy = xv.y - mv.y,
                  dz = xv.z - mv.z, dw = xv.w - mv.w;
            d2 += dx*dx + dy*dy + dz*dz + dw*dw;
        }
    }
    float dd = sqrtf(d2);
    float r = dd / s2[tid];
    float lg = -(r * r);

    float mx = lg;
    #pragma unroll
    for (int msk = 1; msk <= 32; msk <<= 1) mx = fmaxf(mx, __shfl_xor(mx, msk));
    if (lane == 0) redM[w] = mx;
    __syncthreads();
    float bmx = fmaxf(fmaxf(redM[0], redM[1]), fmaxf(redM[2], redM[3]));
    float d = lg - bmx;
    float e = __expf(d);
    float S = e, T = d * e;
    #pragma unroll
    for (int msk = 1; msk <= 32; msk <<= 1) {
        S += __shfl_xor(S, msk);
        T += __shfl_xor(T, msk);
    }
    if (lane == 0) { redS[w] = S; redT[w] = T; }
    __syncthreads();
    if (tid == 0) {
        float Sa = redS[0] + redS[1] + redS[2] + redS[3];
        float Ta = redT[0] + redT[1] + redT[2] + redT[3];
        float inter = __logf(Sa) - Ta / Sa;
        double intra_d = dred[0] + dred[1] + dred[2] + dred[3];
        float intra = (float)(intra_d / (double)N_ROWS);
        out[0] = intra - inter;   // LAMB = 1
        out[1] = intra;
        out[2] = inter;
    }
}

extern "C" void kernel_launch(void* const* d_in, const int* in_sizes, int n_in,
                              void* d_out, int out_size, void* d_ws, size_t ws_size,
                              hipStream_t stream) {
    const float* x  = (const float*)d_in[0];
    const float* m  = (const float*)d_in[1];
    const float* s1 = (const float*)d_in[2];
    const float* s2 = (const float*)d_in[3];
    float* out = (float*)d_out;

    char* ws = (char*)d_ws;
    unsigned short* mhi_g = (unsigned short*)ws;          // 65536 B
    float* mn2_g  = (float*)(ws + 65536);                 // 1024 B
    float* invs_g = (float*)(ws + 65536 + 1024);          // 1024 B
    float* blocksum = (float*)(ws + 65536 + 2048);        // 2048 * 4 B

    const size_t shbytes = 65536 + 2048 + 32;
    static bool attr_set = false;   // host-side metadata only
    if (!attr_set) {
        (void)hipFuncSetAttribute((const void*)fused_main,
                                  hipFuncAttributeMaxDynamicSharedMemorySize,
                                  (int)shbytes);
        attr_set = true;
    }

    prep<<<dim3(32), dim3(256), 0, stream>>>(m, s1, mhi_g, mn2_g, invs_g);
    fused_main<<<dim3(2048), dim3(512), shbytes, stream>>>(x, mhi_g, mn2_g, invs_g, blocksum);
    finalize<<<dim3(1), dim3(256), 0, stream>>>(blocksum, m, s2, out);
}